// Round 1
// baseline (4103.543 us; speedup 1.0000x reference)
//
#include <hip/hip_runtime.h>
#include <cstdint>
#include <cstddef>

// ---------------------------------------------------------------------------
// Persistent-kernel seq2seq decoder: 2-layer LSTM (H=1024) + Luong dot attn.
// T=256 strictly sequential steps; one persistent kernel, 256 blocks x 256
// threads, hand-rolled grid barrier (all blocks co-resident: 1024 waves).
//
// Per step, 4 phases separated by grid barriers:
//   A: layer-0 LSTM  gates0 = W_ih0·x + W_hh0·h0          (block owns 4 h-dims)
//   B: layer-1 LSTM  gates1 = W_ih1·h0' + W_hh1·h1
//   C: scores_s = enc[s]·h1'  and  y2_j = Wc2[j]·h1'
//   D: attn_h = tanh( (Σ_s e_s·MT[j,s])/Σ_s e_s + y2_j + b_j );  x <- attn_h
// MT[j,s] = Wc1[j]·enc[s] precomputed once in-kernel (block b owns rows 4b..4b+3,
// so MT stays XCD-local). Softmax normalization folds into the MT matvec
// (numer/denom), eliminating a 5th sync phase.
//
// Cross-block data (x, h0', h1', scores) moves via sc1 agent-scope RELAXED
// atomics (always at coherence point) so the barrier needs NO acquire-inv —
// keeping weights resident in each XCD's L2 across barriers.
// ---------------------------------------------------------------------------

#define TSTEPS 256
#define HDIM   1024
#define NBLK   256
#define NTHR   256

// float-index offsets into ws
#define WS_X    0        // x (attn_h feedback) [1024]
#define WS_H0   1024     // h0 double buffer [2][1024]
#define WS_H1   3072     // h1 double buffer [2][1024]
#define WS_C0   5120     // c0 [1024] (block-private slices)
#define WS_C1   6144     // c1 [1024]
#define WS_SC   7168     // scores [1024]
#define WS_Y2   8192     // y2 = Wc2 @ h1' [1024]
#define WS_MT   16384    // MT [1024][1024]
#define SLOTS_OFF_BYTES ((size_t)(WS_MT + 1024 * 1024) * sizeof(float))
#define SLOT_STRIDE 16   // ints (64 B apart)

__device__ __forceinline__ float wred_sum(float v) {
#pragma unroll
  for (int m = 32; m >= 1; m >>= 1) v += __shfl_xor(v, m, 64);
  return v;
}
__device__ __forceinline__ float wred_max(float v) {
#pragma unroll
  for (int m = 32; m >= 1; m >>= 1) v = fmaxf(v, __shfl_xor(v, m, 64));
  return v;
}

// 8-byte agent-scope relaxed load (sc1: always reads the coherence point)
__device__ __forceinline__ float2 aload2(const float* p) {
  unsigned long long u = __hip_atomic_load((unsigned long long*)(uintptr_t)p,
                                           __ATOMIC_RELAXED, __HIP_MEMORY_SCOPE_AGENT);
  float2 r;
  r.x = __uint_as_float((unsigned)u);
  r.y = __uint_as_float((unsigned)(u >> 32));
  return r;
}
__device__ __forceinline__ void astoref(float* p, float v) {
  __hip_atomic_store((unsigned*)p, __float_as_uint(v), __ATOMIC_RELAXED,
                     __HIP_MEMORY_SCOPE_AGENT);
}

// Symmetric grid barrier: block publishes monotone gen into its slot; every
// thread polls one slot. Signed >= compare: 0xAAAAAAAA poison is negative
// (safe initial state) and later-generation overwrites can't deadlock.
// RELAXED everywhere: data already at coherence point via sc1 atomics; the
// __syncthreads (vmcnt drain + full compiler fence) provides ordering.
__device__ __forceinline__ void gbar(int* slots, int gen) {
  __syncthreads();  // drains this block's outstanding (sc1) stores
  if (threadIdx.x == 0)
    __hip_atomic_store(&slots[blockIdx.x * SLOT_STRIDE], gen, __ATOMIC_RELAXED,
                       __HIP_MEMORY_SCOPE_AGENT);
  int ok;
  do {
    int v = __hip_atomic_load(&slots[threadIdx.x * SLOT_STRIDE], __ATOMIC_RELAXED,
                              __HIP_MEMORY_SCOPE_AGENT);
    ok = (v >= gen);
    if (!ok) __builtin_amdgcn_s_sleep(2);
  } while (!__syncthreads_and(ok));
}

__device__ __forceinline__ float sigmoidf_(float x) { return 1.f / (1.f + __expf(-x)); }

// load 16 lane-local floats of a 1024-vector (lane l covers 2l+128i, i=0..7)
__device__ __forceinline__ void load16_plain(const float* base, int l, float* r) {
#pragma unroll
  for (int i = 0; i < 8; ++i) {
    float2 a = *(const float2*)(base + 2 * l + 128 * i);
    r[2 * i] = a.x; r[2 * i + 1] = a.y;
  }
}
__device__ __forceinline__ void load16_agent(const float* base, int l, float* r) {
#pragma unroll
  for (int i = 0; i < 8; ++i) {
    float2 a = aload2(base + 2 * l + 128 * i);
    r[2 * i] = a.x; r[2 * i + 1] = a.y;
  }
}
// partial dot of one 1024-row against lane-local 16 floats
__device__ __forceinline__ float dotrow(const float* row, int l, const float* x) {
  float p = 0.f;
#pragma unroll
  for (int i = 0; i < 8; ++i) {
    float2 wv = *(const float2*)(row + 2 * l + 128 * i);
    p += wv.x * x[2 * i] + wv.y * x[2 * i + 1];
  }
  return p;
}

// one LSTM output dim k: 8 row-dots (i,f,g,o x {ih,hh}), wave-reduce, cell math
__device__ __forceinline__ void lstm_cell(
    int k, int l, const float* __restrict__ wih, const float* __restrict__ whh,
    const float* __restrict__ bih, const float* __restrict__ bhh,
    const float* xr, const float* hr, const float* cold_src, float* cdst,
    float* hdst) {
  float gs[4];
#pragma unroll
  for (int g = 0; g < 4; ++g) {
    const float* wi = wih + (size_t)(g * HDIM + k) * HDIM;
    const float* wh = whh + (size_t)(g * HDIM + k) * HDIM;
    float p = dotrow(wi, l, xr) + dotrow(wh, l, hr);
    gs[g] = wred_sum(p);
  }
  if (l == 0) {
    float ig = sigmoidf_(gs[0] + bih[k] + bhh[k]);
    float fg = sigmoidf_(gs[1] + bih[HDIM + k] + bhh[HDIM + k]);
    float gg = tanhf(gs[2] + bih[2 * HDIM + k] + bhh[2 * HDIM + k]);
    float og = sigmoidf_(gs[3] + bih[3 * HDIM + k] + bhh[3 * HDIM + k]);
    float cn = fg * cold_src[k] + ig * gg;
    cdst[k] = cn;                      // block-private: plain store
    astoref(hdst + k, og * tanhf(cn)); // cross-block: sc1 store
  }
}

__global__ void __launch_bounds__(NTHR) decoder_persist(
    const float* __restrict__ enc,   // [1024,1024]
    const float* __restrict__ hid,   // [2,1024]
    const float* __restrict__ cell,  // [2,1024]
    const float* __restrict__ w_ih,  // [2,4096,1024]
    const float* __restrict__ w_hh,  // [2,4096,1024]
    const float* __restrict__ b_ih,  // [2,4096]
    const float* __restrict__ b_hh,  // [2,4096]
    const float* __restrict__ wcat,  // [1024,2048]
    const float* __restrict__ bcat,  // [1024]
    float* __restrict__ out,         // [256,1024]
    float* __restrict__ ws) {
  const int b = blockIdx.x;
  const int tid = threadIdx.x;
  const int w = tid >> 6;   // wave 0..3
  const int l = tid & 63;   // lane
  int* slots = (int*)((char*)ws + SLOTS_OFF_BYTES);
  float* MT = ws + WS_MT;

  // ---- pre-phase: MT[j][s] = sum_h Wc1[j,h] * enc[s,h], block owns j=4b..4b+3
  {
    const int j0 = b << 2;
    const float* wr0 = wcat + (size_t)(j0 + 0) * 2048;
    const float* wr1 = wcat + (size_t)(j0 + 1) * 2048;
    const float* wr2 = wcat + (size_t)(j0 + 2) * 2048;
    const float* wr3 = wcat + (size_t)(j0 + 3) * 2048;
#pragma unroll
    for (int ii = 0; ii < 4; ++ii) {
      int s = (w << 8) + (ii << 6) + l;
      const float* er = enc + (size_t)s * HDIM;
      float a0 = 0.f, a1 = 0.f, a2 = 0.f, a3 = 0.f;
      for (int hh = 0; hh < HDIM; hh += 4) {
        float4 ev = *(const float4*)(er + hh);
        float4 w0 = *(const float4*)(wr0 + hh);  // lane-uniform -> scalar loads
        float4 w1 = *(const float4*)(wr1 + hh);
        float4 w2 = *(const float4*)(wr2 + hh);
        float4 w3 = *(const float4*)(wr3 + hh);
        a0 += ev.x * w0.x + ev.y * w0.y + ev.z * w0.z + ev.w * w0.w;
        a1 += ev.x * w1.x + ev.y * w1.y + ev.z * w1.z + ev.w * w1.w;
        a2 += ev.x * w2.x + ev.y * w2.y + ev.z * w2.z + ev.w * w2.w;
        a3 += ev.x * w3.x + ev.y * w3.y + ev.z * w3.z + ev.w * w3.w;
      }
      MT[(size_t)(j0 + 0) * HDIM + s] = a0;
      MT[(size_t)(j0 + 1) * HDIM + s] = a1;
      MT[(size_t)(j0 + 2) * HDIM + s] = a2;
      MT[(size_t)(j0 + 3) * HDIM + s] = a3;
    }
  }
  __syncthreads();  // MT consumed only by this block (phase D)

  const float* wih1 = w_ih + (size_t)4096 * 1024;
  const float* whh1 = w_hh + (size_t)4096 * 1024;
  const float* bih1 = b_ih + 4096;
  const float* bhh1 = b_hh + 4096;

  for (int t = 0; t < TSTEPS; ++t) {
    const int par = t & 1;
    float* h0r = ws + WS_H0 + par * 1024;
    float* h0w = ws + WS_H0 + (par ^ 1) * 1024;
    float* h1r = ws + WS_H1 + par * 1024;
    float* h1w = ws + WS_H1 + (par ^ 1) * 1024;

    // ===== Phase A: layer-0 LSTM, k = 4b + w =====
    {
      const int k = (b << 2) + w;
      float xr[16], hr[16];
      if (t == 0) {
        load16_plain(hid + HDIM, l, xr);  // x0 = hidden_state[-1] (layer 1)
        load16_plain(hid, l, hr);         // h0 init
      } else {
        load16_agent(ws + WS_X, l, xr);
        load16_agent(h0r, l, hr);
      }
      const float* csrc = (t == 0) ? cell : (ws + WS_C0);
      lstm_cell(k, l, w_ih, w_hh, b_ih, b_hh, xr, hr, csrc, ws + WS_C0, h0w);
    }
    gbar(slots, t * 4 + 1);

    // ===== Phase B: layer-1 LSTM, input = h0', state h1 =====
    {
      const int k = (b << 2) + w;
      float xr[16], hr[16];
      load16_agent(h0w, l, xr);  // h0' (always ws)
      if (t == 0) load16_plain(hid + HDIM, l, hr);
      else        load16_agent(h1r, l, hr);
      const float* csrc = (t == 0) ? (cell + HDIM) : (ws + WS_C1);
      lstm_cell(k, l, wih1, whh1, bih1, bhh1, xr, hr, csrc, ws + WS_C1, h1w);
    }
    gbar(slots, t * 4 + 2);

    // ===== Phase C: scores_s = enc[s]·h1'  (waves 0,1)  |  y2_j = Wc2[j]·h1' (waves 2,3)
    {
      float hv[16];
      load16_agent(h1w, l, hv);
#pragma unroll
      for (int rr = 0; rr < 2; ++rr) {
        int r = (b << 2) + ((w & 1) << 1) + rr;
        const float* row = (w < 2) ? (enc + (size_t)r * HDIM)
                                   : (wcat + (size_t)r * 2048 + HDIM);
        float p = dotrow(row, l, hv);
        p = wred_sum(p);
        if (l == 0) {
          if (w < 2) astoref(ws + WS_SC + r, p);  // cross-block
          else       ws[WS_Y2 + r] = p;           // same-block consumer
        }
      }
    }
    gbar(slots, t * 4 + 3);

    // ===== Phase D: softmax-weighted MT matvec + concat-proj tanh =====
    {
      const int j = (b << 2) + w;
      float sc[16];
      load16_agent(ws + WS_SC, l, sc);
      float m = sc[0];
#pragma unroll
      for (int i = 1; i < 16; ++i) m = fmaxf(m, sc[i]);
      m = wred_max(m);
      float e[16];
      float d = 0.f;
#pragma unroll
      for (int i = 0; i < 16; ++i) { e[i] = __expf(sc[i] - m); d += e[i]; }
      d = wred_sum(d);
      const float* mrow = MT + (size_t)j * HDIM;
      float p = 0.f;
#pragma unroll
      for (int i = 0; i < 8; ++i) {
        float2 mv = *(const float2*)(mrow + 2 * l + 128 * i);
        p += mv.x * e[2 * i] + mv.y * e[2 * i + 1];
      }
      p = wred_sum(p);
      if (l == 0) {
        float a = tanhf(p / d + ws[WS_Y2 + j] + bcat[j]);
        astoref(ws + WS_X + j, a);          // next step's input
        out[(size_t)t * HDIM + j] = a;      // kernel output
      }
    }
    gbar(slots, t * 4 + 4);
  }
}

extern "C" void kernel_launch(void* const* d_in, const int* in_sizes, int n_in,
                              void* d_out, int out_size, void* d_ws, size_t ws_size,
                              hipStream_t stream) {
  // d_in: 0 input_sequence (UNUSED by reference), 1 encoder_out, 2 hidden_state,
  //       3 cell_state, 4 w_ih, 5 w_hh, 6 b_ih, 7 b_hh, 8 w_concat, 9 b_concat
  const float* enc  = (const float*)d_in[1];
  const float* hid  = (const float*)d_in[2];
  const float* cel  = (const float*)d_in[3];
  const float* wih  = (const float*)d_in[4];
  const float* whh  = (const float*)d_in[5];
  const float* bih  = (const float*)d_in[6];
  const float* bhh  = (const float*)d_in[7];
  const float* wcat = (const float*)d_in[8];
  const float* bcat = (const float*)d_in[9];
  float* out = (float*)d_out;
  float* ws  = (float*)d_ws;

  hipLaunchKernelGGL(decoder_persist, dim3(NBLK), dim3(NTHR), 0, stream,
                     enc, hid, cel, wih, whh, bih, bhh, wcat, bcat, out, ws);
}